// Round 20
// baseline (438.173 us; speedup 1.0000x reference)
//
#include <hip/hip_runtime.h>

typedef __attribute__((ext_vector_type(8))) short short8;
typedef __attribute__((ext_vector_type(4))) float f32x4;
typedef unsigned int u32;

#define CIN   128
#define COUT  256
#define H     112
#define W     112
#define OH    110
#define OW    110
#define KHW   9
#define TH    8
#define TW    32
#define IWW   34              // TW+2
#define NPIX  340             // 10*34
#define XB    (NPIX*8*16)     // 43520 B per x half-buffer
#define WB    32768           // 256 cout * 8 slots * 16B per w tap buffer
#define ROWB  (IWW*128)       // 4352

__device__ __forceinline__ short f2b(float f) {
  unsigned u = __builtin_bit_cast(unsigned, f);
  unsigned r = (u + 0x7FFFu + ((u >> 16) & 1u)) >> 16;  // RNE
  return (short)r;
}

__device__ __forceinline__ void gload16(const void* g, void* l) {
  __builtin_amdgcn_global_load_lds(
      (const __attribute__((address_space(1))) u32*)g,
      (__attribute__((address_space(3))) u32*)l, 16, 0, 0);
}

// R20: T3+T4 port (m201 8-phase template) — 1 block x 8 waves/CU, raw
// s_barrier + counted vmcnt (NEVER a full __syncthreads drain in the loop).
// Per tap: 4 phases {ds_reads -> staging issue -> s_barrier -> lgkmcnt(0)
// + sched_barrier(0) [rule #18] -> setprio(1) 16 MFMA setprio(0) ->
// s_barrier}. bf[4] held across the mi-half phases (avg 6 reads/phase).
// w(st+1) DMA split 2+2 over P1/P3; stage-end counted vmcnt in P4:
// vmcnt(1) when an x-dribble chunk rides behind (taps 0..4 of hh0),
// else vmcnt(0). x half-1 DMA dribbles into its OWN buffer (taps 0..5)
// -> no barriers needed for it. Layouts = R13 (proven 0-conflict):
// x byte(p,G)=p*128+((G^(ix&7))<<4) (row-invariant key, imm row walks);
// w byte(c,G)=c*128+((G^(c&7))<<4); DMA linear dest + source-preswizzle
// (m173); OOB -> zero page (wave-uniform-base contract).
// Wave tile 128cout x 64px, acc[8][4]=128 AGPR -> 2 waves/SIMD budget.

template<bool XT, bool WT>
__global__ __launch_bounds__(512, 2)
void conv_main(const float* __restrict__ x, const float* __restrict__ wgt,
               const short* __restrict__ wt, const short* __restrict__ xt,
               const short* __restrict__ zp, float* __restrict__ out) {
  __shared__ __align__(16) char smem[2*XB + 2*WB];   // 152576 B, 1 block/CU
  char* sx = smem;                 // [2][XB] x half buffers
  char* sw = smem + 2*XB;          // [2][WB] w tap buffers

  const int tid = threadIdx.x;

  // XCD-chunked bijective swizzle (1792 % 8 == 0)
  const int nb  = gridDim.x;
  const int swz = (blockIdx.x & 7) * (nb >> 3) + (blockIdx.x >> 3);
  const int b    = swz / 56;             // 4 tw * 14 th
  const int rem  = swz - b * 56;
  const int t_w  = rem / 14;
  const int t_h  = rem - t_w * 14;
  const int h0 = t_h * TH, w0 = t_w * TW;

  auto xsrc = [&](int u, int hh) -> const short* {
    int p = u >> 3;
    int iy = p / IWW, ix = p - iy * IWW;
    int Geff = (u & 7) ^ (ix & 7);
    int gy = h0 + iy, gx = w0 + ix;
    return (gy < H && gx < W)
        ? xt + (size_t)b*(H*W*CIN) + ((size_t)gy*W + gx)*CIN + hh*64 + Geff*8
        : zp;
  };
  auto stage_x_full = [&](int hh) {
    if (XT) {
      #pragma unroll
      for (int it = 0; it < 6; ++it) {
        int u = it*512 + tid;
        if (u < 8*NPIX) gload16(xsrc(u, hh), sx + hh*XB + u*16);
      }
    } else {
      const float* xh = x + (size_t)b * CIN * (H*W) + (size_t)(hh*64) * (H*W);
      for (int u = tid; u < 8 * NPIX; u += 512) {
        int G = u / NPIX, p = u - G * NPIX;
        int iy = p / IWW, ix = p - iy * IWW;
        int gy = h0 + iy, gx = w0 + ix;
        short8 v = {0,0,0,0,0,0,0,0};
        if (gy < H && gx < W) {
          const float* s = xh + (size_t)(G*8) * (H*W) + gy * W + gx;
          #pragma unroll
          for (int j = 0; j < 8; ++j) v[j] = f2b(s[j * (H*W)]);
        }
        *(short8*)(sx + hh*XB + p*128 + ((G ^ (ix & 7)) << 4)) = v;
      }
    }
  };
  auto stage_x1_chunk = [&](int c) {      // XT only: 512 slots per chunk
    int u = c*512 + tid;
    if (u < 8*NPIX) gload16(xsrc(u, 1), sx + XB + u*16);
  };

  int wgoff[4];
  #pragma unroll
  for (int it = 0; it < 4; ++it) {
    int slot = it*512 + tid;               // 2048 slots of 16B
    int c = slot >> 3, gsw = (slot & 7) ^ (c & 7);
    wgoff[it] = c * CIN + gsw * 8;
  }
  auto stage_w_pair = [&](int tap, int hh, int buf, int pair) {
    if (WT) {
      const short* base = wt + tap*(COUT*CIN) + hh*64;
      #pragma unroll
      for (int q = 0; q < 2; ++q) {
        int it = pair*2 + q;
        gload16(base + wgoff[it], sw + buf*WB + (it*512 + tid)*16);
      }
    } else {
      #pragma unroll
      for (int q = 0; q < 2; ++q) {
        int it = pair*2 + q;
        int slot = it*512 + tid;
        int c = slot >> 3, gsw = (slot & 7) ^ (c & 7);
        short8 v;
        #pragma unroll
        for (int j = 0; j < 8; ++j) {
          int cin = hh*64 + gsw*8 + j;
          v[j] = f2b(wgt[c*(CIN*KHW) + cin*KHW + tap]);
        }
        *(short8*)(sw + buf*WB + slot*16) = v;
      }
    }
  };

  const int lane = tid & 63;
  const int wid  = tid >> 6;       // 0..7
  const int wm = wid & 1;          // cout half [wm*128, +128)
  const int wn = wid >> 1;         // 0..3 -> rows {2wn, 2wn+1}
  const int l15 = lane & 15;
  const int kgrp = lane >> 4;      // 0..3
  const int l7 = l15 & 7;

  int aoff[2], boff[2][3];
  #pragma unroll
  for (int s = 0; s < 2; ++s) {
    int g = s*4 + kgrp;
    aoff[s] = 2*XB + (wm*128 + l15)*128 + ((g ^ l7) << 4);
    #pragma unroll
    for (int kw = 0; kw < 3; ++kw) {
      int lk = l15 + kw;
      boff[s][kw] = (2*wn)*ROWB + lk*128 + ((g ^ (lk & 7)) << 4);
    }
  }

  f32x4 acc[8][4] = {};

  stage_x_full(0);
  stage_w_pair(0, 0, 0, 0);
  stage_w_pair(0, 0, 0, 1);
  asm volatile("s_waitcnt vmcnt(0)" ::: "memory");
  asm volatile("s_waitcnt lgkmcnt(0)" ::: "memory");
  __builtin_amdgcn_s_barrier();

  #pragma unroll
  for (int hh = 0; hh < 2; ++hh) {
    #pragma unroll
    for (int tap = 0; tap < 9; ++tap) {
      const int st  = hh*9 + tap;
      const int kh  = tap / 3, kw = tap - (tap/3)*3;
      const int wbuf = (st & 1) * WB;
      const int xoff = hh * XB;
      const int ntap = (st+1) % 9, nhh = (st+1) / 9, nbuf = (st+1) & 1;

      #pragma unroll
      for (int s = 0; s < 2; ++s) {
        short8 bf[4];
        #pragma unroll
        for (int ni = 0; ni < 4; ++ni)
          bf[ni] = *(const short8*)(smem + boff[s][kw] + xoff
                        + (kh + (ni >> 1))*ROWB + (ni & 1)*2048);
        #pragma unroll
        for (int half = 0; half < 2; ++half) {
          short8 a[4];
          #pragma unroll
          for (int mi = 0; mi < 4; ++mi)
            a[mi] = *(const short8*)(smem + aoff[s] + wbuf
                          + (half*4 + mi)*2048);
          // staging issue slots (P1, P3) + stage-end counted wait (P4)
          if (half == 0 && st < 17) stage_w_pair(ntap, nhh, nbuf, s);
          if (s == 1 && half == 1) {
            if (XT && hh == 0 && tap < 5) {
              stage_x1_chunk(tap);                    // rides behind w
              asm volatile("s_waitcnt vmcnt(1)" ::: "memory");
            } else if (XT && hh == 0 && tap == 5) {
              stage_x1_chunk(5);                      // partial chunk
              asm volatile("s_waitcnt vmcnt(0)" ::: "memory");
            } else if (st < 17) {
              asm volatile("s_waitcnt vmcnt(0)" ::: "memory");
            }
          }
          __builtin_amdgcn_s_barrier();
          asm volatile("s_waitcnt lgkmcnt(0)" ::: "memory");
          __builtin_amdgcn_sched_barrier(0);
          __builtin_amdgcn_s_setprio(1);
          #pragma unroll
          for (int mi = 0; mi < 4; ++mi)
            #pragma unroll
            for (int ni = 0; ni < 4; ++ni)
              acc[half*4 + mi][ni] = __builtin_amdgcn_mfma_f32_16x16x32_bf16(
                  a[mi], bf[ni], acc[half*4 + mi][ni], 0, 0, 0);
          __builtin_amdgcn_s_setprio(0);
          if (!XT && st == 8 && s == 1 && half == 1) {
            __builtin_amdgcn_s_barrier();
            stage_x_full(1);                          // fallback restage
            asm volatile("s_waitcnt lgkmcnt(0)" ::: "memory");
          }
          __builtin_amdgcn_s_barrier();
        }
      }
    }
  }

  // ---- epilogue: C layout col=l15 (px), row=4*kgrp+r (cout) [m89] ----
  float* ob = out + (size_t)b * COUT * (OH*OW);
  #pragma unroll
  for (int ni = 0; ni < 4; ++ni) {
    int oh = h0 + 2*wn + (ni >> 1);
    int ow = w0 + (ni & 1)*16 + l15;
    if (oh < OH && ow < OW) {
      #pragma unroll
      for (int mi = 0; mi < 8; ++mi) {
        #pragma unroll
        for (int r = 0; r < 4; ++r) {
          int cout = wm*128 + mi*16 + kgrp*4 + r;
          ob[(size_t)cout*(OH*OW) + oh*OW + ow] = acc[mi][ni][r];
        }
      }
    }
  }
}

// one-time weight transpose+cvt: wt[tap][cout][cin] bf16; zeros the zero page.
__global__ void wprep(const float* __restrict__ wgt, short* __restrict__ wt,
                      short* __restrict__ zp) {
  int idx = blockIdx.x * 256 + threadIdx.x;
  if (idx < 128) zp[idx] = 0;
  if (idx >= KHW*COUT*CIN) return;
  int khw  = idx / (COUT*CIN);
  int rem  = idx - khw*(COUT*CIN);
  int cout = rem >> 7, cin = rem & 127;
  wt[idx] = f2b(wgt[cout*(CIN*KHW) + cin*KHW + khw]);
}

// one-time x transpose+cvt: xt[b][h][w][cin] bf16, via padded LDS tile.
__global__ __launch_bounds__(256)
void xprep(const float* __restrict__ x, short* __restrict__ xt) {
  __shared__ short lsh[CIN * 113];   // 28928 B
  const int bh = blockIdx.x;
  const int b = bh / H, h = bh - b * H;
  const float* src = x + ((size_t)b * CIN * H + h) * W;
  for (int u = threadIdx.x; u < CIN * W; u += 256) {
    int c = u / W, w = u - c * W;
    lsh[c * 113 + w] = f2b(src[(size_t)c * (H*W) + w]);
  }
  __syncthreads();
  short* dst = xt + (size_t)bh * (W * CIN);
  for (int o = threadIdx.x; o < W * CIN / 8; o += 256) {   // 1792
    int w = o >> 4, s = o & 15;
    short8 v;
    #pragma unroll
    for (int j = 0; j < 8; ++j) v[j] = lsh[(s*8 + j) * 113 + w];
    *(short8*)(dst + o * 8) = v;
  }
}

extern "C" void kernel_launch(void* const* d_in, const int* in_sizes, int n_in,
                              void* d_out, int out_size, void* d_ws, size_t ws_size,
                              hipStream_t stream) {
  const float* x   = (const float*)d_in[0];
  const float* wgt = (const float*)d_in[1];
  float* out = (float*)d_out;
  const size_t wt_bytes = (size_t)(KHW*COUT*CIN) * sizeof(short);   // 589824
  const size_t zp_bytes = 256;
  const size_t xt_bytes = (size_t)32 * H * W * CIN * sizeof(short); // 102.76 MB
  dim3 grid(1792);   // 4 tw x 14 th x 32 b
  if (ws_size >= wt_bytes + zp_bytes + xt_bytes) {
    short* wt = (short*)d_ws;
    short* zp = (short*)((char*)d_ws + wt_bytes);
    short* xt = (short*)((char*)d_ws + wt_bytes + zp_bytes);
    wprep<<<(KHW*COUT*CIN + 255)/256, 256, 0, stream>>>(wgt, wt, zp);
    xprep<<<32 * H, 256, 0, stream>>>(x, xt);
    conv_main<true, true><<<grid, 512, 0, stream>>>(x, wgt, wt, xt, zp, out);
  } else if (ws_size >= wt_bytes + zp_bytes) {
    short* wt = (short*)d_ws;
    short* zp = (short*)((char*)d_ws + wt_bytes);
    wprep<<<(KHW*COUT*CIN + 255)/256, 256, 0, stream>>>(wgt, wt, zp);
    conv_main<false, true><<<grid, 512, 0, stream>>>(x, wgt, wt, nullptr, zp, out);
  } else {
    conv_main<false, false><<<grid, 512, 0, stream>>>(x, wgt, nullptr, nullptr, nullptr, out);
  }
}

// Round 21
// 339.240 us; speedup vs baseline: 1.2916x; 1.2916x over previous
//
#include <hip/hip_runtime.h>

typedef __attribute__((ext_vector_type(8))) short short8;
typedef __attribute__((ext_vector_type(4))) float f32x4;
typedef unsigned int u32;

#define CIN   128
#define COUT  256
#define H     112
#define W     112
#define OH    110
#define OW    110
#define KHW   9
#define TH    8
#define TW    32
#define IWW   34              // TW+2
#define NPIX  340             // 10*34
#define XB    (NPIX*8*16)     // 43520 B: x half-tile, 2720 16B slots
#define WB    16384           // w tap-half: 128 cout * 8 slots * 16B
#define ROWB  (IWW*128)       // 4352: LDS bytes per x row

__device__ __forceinline__ short f2b(float f) {
  unsigned u = __builtin_bit_cast(unsigned, f);
  unsigned r = (u + 0x7FFFu + ((u >> 16) & 1u)) >> 16;  // RNE
  return (short)r;
}

__device__ __forceinline__ void gload16(const void* g, void* l) {
  __builtin_amdgcn_global_load_lds(
      (const __attribute__((address_space(1))) u32*)g,
      (__attribute__((address_space(3))) u32*)l, 16, 0, 0);
}

// Best-verified configuration (R13: conv 256us, MfmaUtil 46.5%, 0 bank
// conflicts, no spill). This is the plain-HIP 2-barrier-schedule optimum:
// 2 waves/SIMD (252/256 regs: 124 VGPR + 128 AGPR acc[4][8]) and
// 2 blocks/CU (76.3 KB LDS) — both resource walls are exactly met; every
// register- or LDS-hungrier variant (R12/R14/R17/R18/R20) spilled or lost
// occupancy, every scheduling nudge (R11/R16/R19) was null.
//   x LDS: byte(p,G) = p*128 + ((G ^ (ix&7))<<4), ix=p%34 — row-invariant
//   swizzle key => all kh/row walks are +4352-byte immediates; 0 conflicts.
//   w LDS: byte(c,G) = c*128 + ((G^(c&7))<<4), double-buffered per tap.
//   DMA: global_load_lds with linear dest + swizzle pre-applied on the
//   per-lane GLOBAL source (m173); OOB lanes -> zero page (wave-uniform
//   base contract); only prefix tail-masking.
//   XCD-chunked bijective block swizzle (3584 % 8 == 0).

template<bool XT, bool WT>
__global__ __launch_bounds__(256, 2)
void conv_main(const float* __restrict__ x, const float* __restrict__ wgt,
               const short* __restrict__ wt, const short* __restrict__ xt,
               const short* __restrict__ zp, float* __restrict__ out) {
  __shared__ __align__(16) char smem[XB + 2*WB];   // 76288 B -> 2 blocks/CU
  char* sx = smem;
  char* sw = smem + XB;

  const int tid = threadIdx.x;

  // XCD-chunked bijective swizzle (3584 % 8 == 0)
  const int nb  = gridDim.x;
  const int swz = (blockIdx.x & 7) * (nb >> 3) + (blockIdx.x >> 3);
  const int b    = swz / 112;            // 2 cblk * 4 tw * 14 th
  const int rem  = swz - b * 112;
  const int cblk = rem / 56;
  const int rem2 = rem - cblk * 56;
  const int t_w  = rem2 / 14;
  const int t_h  = rem2 - t_w * 14;
  const int h0 = t_h * TH, w0 = t_w * TW;

  auto stage_x = [&](int hh) {
    if (XT) {
      const short* xtb = xt + (size_t)b * (H*W*CIN);
      #pragma unroll
      for (int it = 0; it < 11; ++it) {
        int u = it*256 + tid;            // slot index, 2720 total
        if (u < 8*NPIX) {                // prefix-masked tail only: safe
          int p = u >> 3;                // pixel 0..339
          int iy = p / IWW, ix = p - iy * IWW;
          int Geff = (u & 7) ^ (ix & 7); // pre-swizzled source fragment
          int gy = h0 + iy, gx = w0 + ix;
          const short* src = (gy < H && gx < W)
              ? xtb + ((size_t)gy*W + gx)*CIN + hh*64 + Geff*8
              : zp;                      // OOB -> zero page (per-lane src ok)
          gload16(src, sx + u*16);
        }
      }
    } else {
      const float* xh = x + (size_t)b * CIN * (H*W) + (size_t)(hh*64) * (H*W);
      for (int u = tid; u < 8 * NPIX; u += 256) {
        int G = u / NPIX, p = u - G * NPIX;
        int iy = p / IWW, ix = p - iy * IWW;
        int gy = h0 + iy, gx = w0 + ix;
        short8 v = {0,0,0,0,0,0,0,0};
        if (gy < H && gx < W) {
          const float* s = xh + (size_t)(G*8) * (H*W) + gy * W + gx;
          #pragma unroll
          for (int j = 0; j < 8; ++j) v[j] = f2b(s[j * (H*W)]);
        }
        *(short8*)(sx + p*128 + ((G ^ (ix & 7)) << 4)) = v;
      }
    }
  };

  auto stage_w = [&](int st, int buf) {
    int hh = st / 9, tap = st - hh * 9;
    if (WT) {
      const short* base = wt + (size_t)tap * (COUT*CIN)
                             + (size_t)(cblk*128) * CIN + hh * 64;
      #pragma unroll
      for (int it = 0; it < 4; ++it) {
        int slot = it * 256 + tid;            // 1024 slots of 16B
        int c = slot >> 3, gsw = (slot & 7) ^ (c & 7);
        gload16(base + c * CIN + gsw * 8, sw + buf*WB + slot * 16);
      }
    } else {
      #pragma unroll
      for (int it = 0; it < 4; ++it) {
        int slot = it * 256 + tid;
        int c = slot >> 3, gsw = (slot & 7) ^ (c & 7);
        int cout = cblk*128 + c;
        short8 v;
        #pragma unroll
        for (int j = 0; j < 8; ++j) {
          int cin = hh*64 + gsw*8 + j;
          v[j] = f2b(wgt[cout*(CIN*KHW) + cin*KHW + tap]);
        }
        *(short8*)(sw + buf*WB + slot * 16) = v;
      }
    }
  };

  const int lane = tid & 63;
  const int wid  = tid >> 6;      // 0..3
  const int wm = wid >> 1;        // 0..1 -> couts [wm*64, +64) of block's 128
  const int wn = wid & 1;         // 0..1 -> rows [wn*4, +4)
  const int l15 = lane & 15;
  const int kgrp = lane >> 4;     // 0..3

  // loop-invariant address bases
  int arow[4];
  #pragma unroll
  for (int mi = 0; mi < 4; ++mi) arow[mi] = (wm*64 + mi*16 + l15) * 128;
  const int l7 = l15 & 7;

  f32x4 acc[4][8] = {};

  stage_x(0);
  stage_w(0, 0);
  __syncthreads();

  for (int st = 0; st < 18; ++st) {          // 2 cin-halves x 9 taps
    const int tap = st % 9;
    const int kh = tap / 3, kw = tap - (tap/3)*3;
    const char* swb = sw + (st & 1) * WB;
    const int brow = (4*wn + kh) * ROWB;     // B row base (bytes)

    #pragma unroll
    for (int s = 0; s < 2; ++s) {            // two K=32 steps over 64 cins
      const int g = s*4 + kgrp;
      const int akey = (g ^ l7) << 4;
      const int bkey = (g ^ ((l15 + kw) & 7)) << 4;
      const char* ab = swb + akey;
      const char* bb0 = sx + brow + (l15 + kw)*128 + bkey;   // cg=0
      const char* bb1 = bb0 + 16*128;                        // cg=1

      short8 a[4];
      #pragma unroll
      for (int mi = 0; mi < 4; ++mi)
        a[mi] = *(const short8*)(ab + arow[mi]);
      short8 bf[8];
      #pragma unroll
      for (int r = 0; r < 4; ++r) {          // all offsets = imm r*4352
        bf[2*r]   = *(const short8*)(bb0 + r*ROWB);
        bf[2*r+1] = *(const short8*)(bb1 + r*ROWB);
      }

      if (s == 0 && st + 1 < 18)             // issue w-DMA off critical path
        stage_w(st + 1, (st + 1) & 1);

      __builtin_amdgcn_s_setprio(1);
      #pragma unroll
      for (int mi = 0; mi < 4; ++mi)
        #pragma unroll
        for (int ni = 0; ni < 8; ++ni)
          acc[mi][ni] = __builtin_amdgcn_mfma_f32_16x16x32_bf16(a[mi], bf[ni], acc[mi][ni], 0, 0, 0);
      __builtin_amdgcn_s_setprio(0);
    }

    if (st == 8) {
      __syncthreads();      // x half-0 readers done; w(9) DMA drained here
      stage_x(1);
      __syncthreads();      // drains x half-1 DMA
    } else {
      __syncthreads();
    }
  }

  // ---- epilogue: C layout col=l15 (px), row=4*kgrp+r (cout) [m89] ----
  float* ob = out + (size_t)b * COUT * (OH*OW);
  #pragma unroll
  for (int ni = 0; ni < 8; ++ni) {
    int oh = h0 + 4*wn + (ni >> 1);
    int ow = w0 + (ni & 1)*16 + l15;
    if (oh < OH && ow < OW) {
      #pragma unroll
      for (int mi = 0; mi < 4; ++mi) {
        #pragma unroll
        for (int r = 0; r < 4; ++r) {
          int cout = cblk*128 + wm*64 + mi*16 + kgrp*4 + r;
          ob[(size_t)cout*(OH*OW) + oh*OW + ow] = acc[mi][ni][r];
        }
      }
    }
  }
}

// one-time weight transpose+cvt: wt[tap][cout][cin] bf16; also zeros the
// 256-B zero page that follows wt in the workspace.
__global__ void wprep(const float* __restrict__ wgt, short* __restrict__ wt,
                      short* __restrict__ zp) {
  int idx = blockIdx.x * 256 + threadIdx.x;
  if (idx < 128) zp[idx] = 0;
  if (idx >= KHW*COUT*CIN) return;
  int khw  = idx / (COUT*CIN);
  int rem  = idx - khw*(COUT*CIN);
  int cout = rem >> 7, cin = rem & 127;
  wt[idx] = f2b(wgt[cout*(CIN*KHW) + cin*KHW + khw]);
}

// one-time x transpose+cvt: xt[b][h][w][cin] bf16, via padded LDS tile.
__global__ __launch_bounds__(256)
void xprep(const float* __restrict__ x, short* __restrict__ xt) {
  __shared__ short lsh[CIN * 113];   // 28928 B
  const int bh = blockIdx.x;
  const int b = bh / H, h = bh - b * H;
  const float* src = x + ((size_t)b * CIN * H + h) * W;
  for (int u = threadIdx.x; u < CIN * W; u += 256) {
    int c = u / W, w = u - c * W;
    lsh[c * 113 + w] = f2b(src[(size_t)c * (H*W) + w]);
  }
  __syncthreads();
  short* dst = xt + (size_t)bh * (W * CIN);
  for (int o = threadIdx.x; o < W * CIN / 8; o += 256) {   // 1792
    int w = o >> 4, s = o & 15;
    short8 v;
    #pragma unroll
    for (int j = 0; j < 8; ++j) v[j] = lsh[(s*8 + j) * 113 + w];
    *(short8*)(dst + o * 8) = v;
  }
}

extern "C" void kernel_launch(void* const* d_in, const int* in_sizes, int n_in,
                              void* d_out, int out_size, void* d_ws, size_t ws_size,
                              hipStream_t stream) {
  const float* x   = (const float*)d_in[0];
  const float* wgt = (const float*)d_in[1];
  float* out = (float*)d_out;
  const size_t wt_bytes = (size_t)(KHW*COUT*CIN) * sizeof(short);   // 589824
  const size_t zp_bytes = 256;
  const size_t xt_bytes = (size_t)32 * H * W * CIN * sizeof(short); // 102.76 MB
  dim3 grid(3584);   // 2 cblk x 4 tw x 14 th x 32 b
  if (ws_size >= wt_bytes + zp_bytes + xt_bytes) {
    short* wt = (short*)d_ws;
    short* zp = (short*)((char*)d_ws + wt_bytes);
    short* xt = (short*)((char*)d_ws + wt_bytes + zp_bytes);
    wprep<<<(KHW*COUT*CIN + 255)/256, 256, 0, stream>>>(wgt, wt, zp);
    xprep<<<32 * H, 256, 0, stream>>>(x, xt);
    conv_main<true, true><<<grid, 256, 0, stream>>>(x, wgt, wt, xt, zp, out);
  } else if (ws_size >= wt_bytes + zp_bytes) {
    short* wt = (short*)d_ws;
    short* zp = (short*)((char*)d_ws + wt_bytes);
    wprep<<<(KHW*COUT*CIN + 255)/256, 256, 0, stream>>>(wgt, wt, zp);
    conv_main<false, true><<<grid, 256, 0, stream>>>(x, wgt, wt, nullptr, zp, out);
  } else {
    conv_main<false, false><<<grid, 256, 0, stream>>>(x, wgt, nullptr, nullptr, nullptr, out);
  }
}

// Round 22
// 331.704 us; speedup vs baseline: 1.3210x; 1.0227x over previous
//
#include <hip/hip_runtime.h>

typedef __attribute__((ext_vector_type(8))) short short8;
typedef __attribute__((ext_vector_type(4))) float f32x4;
typedef unsigned int u32;

#define CIN   128
#define COUT  256
#define H     112
#define W     112
#define OH    110
#define OW    110
#define KHW   9
#define TH    8
#define WB    16384           // w tap-half: 128 cout * 8 slots * 16B
#define XBMAX (340*128)       // NCG=2 x half-tile (43520 B)

__device__ __forceinline__ short f2b(float f) {
  unsigned u = __builtin_bit_cast(unsigned, f);
  unsigned r = (u + 0x7FFFu + ((u >> 16) & 1u)) >> 16;  // RNE
  return (short)r;
}

__device__ __forceinline__ void gload16(const void* g, void* l) {
  __builtin_amdgcn_global_load_lds(
      (const __attribute__((address_space(1))) u32*)g,
      (__attribute__((address_space(3))) u32*)l, 16, 0, 0);
}

// R22 = R13 (reproduced optimum: conv 257us, MfmaUtil 46.5%, 0 conflicts)
// + mixed-width tiles to kill coverage waste: tw 0..2 are 32-px tiles
// (NCG=2, acc[4][8]) and tw==3 is a 16-px tile (NCG=1, acc[4][4]) covering
// px 96..111 -> w-coverage 112/110 instead of 128/110 (-12% MFMA+LDS work
// on 25% of blocks). Single launch, block-uniform branch; barrier structure
// per stage identical in both paths. All R13 machinery unchanged:
//   x LDS byte(p,G) = p*128 + ((G^(ix&7))<<4), ix = p mod IWW (row-invariant
//   key -> row/kh walks are pure byte immediates; measured 0 conflicts);
//   w LDS byte(c,G) = c*128 + ((G^(c&7))<<4), double-buffered per tap;
//   DMA linear dest + swizzle pre-applied on per-lane GLOBAL source (m173);
//   OOB lanes -> zero page (wave-uniform-base contract); prefix tails only;
//   XCD-chunked bijective block swizzle (3584 % 8 == 0).

template<int NCG, bool XT, bool WT>
__device__ __forceinline__
void conv_tile(char* smem, const float* __restrict__ x,
               const float* __restrict__ wgt, const short* __restrict__ wt,
               const short* __restrict__ xt, const short* __restrict__ zp,
               float* __restrict__ out, int b, int cblk, int h0, int w0,
               int tid) {
  constexpr int IWW_  = 16*NCG + 2;
  constexpr int NPIX_ = 10 * IWW_;
  constexpr int XB_   = NPIX_ * 128;
  constexpr int ROWB_ = IWW_ * 128;
  constexpr int NITX  = (8*NPIX_ + 255) / 256;
  constexpr int NREP  = 4 * NCG;

  char* sx = smem;
  char* sw = smem + XB_;

  auto stage_x = [&](int hh) {
    if (XT) {
      const short* xtb = xt + (size_t)b * (H*W*CIN);
      #pragma unroll
      for (int it = 0; it < NITX; ++it) {
        int u = it*256 + tid;
        if (u < 8*NPIX_) {               // prefix-masked tail only: safe
          int p = u >> 3;
          int iy = p / IWW_, ix = p - iy * IWW_;
          int Geff = (u & 7) ^ (ix & 7); // pre-swizzled source fragment
          int gy = h0 + iy, gx = w0 + ix;
          const short* src = (gy < H && gx < W)
              ? xtb + ((size_t)gy*W + gx)*CIN + hh*64 + Geff*8
              : zp;                      // OOB -> zero page
          gload16(src, sx + u*16);
        }
      }
    } else {
      const float* xh = x + (size_t)b * CIN * (H*W) + (size_t)(hh*64) * (H*W);
      for (int u = tid; u < 8 * NPIX_; u += 256) {
        int G = u / NPIX_, p = u - G * NPIX_;
        int iy = p / IWW_, ix = p - iy * IWW_;
        int gy = h0 + iy, gx = w0 + ix;
        short8 v = {0,0,0,0,0,0,0,0};
        if (gy < H && gx < W) {
          const float* s = xh + (size_t)(G*8) * (H*W) + gy * W + gx;
          #pragma unroll
          for (int j = 0; j < 8; ++j) v[j] = f2b(s[j * (H*W)]);
        }
        *(short8*)(sx + p*128 + ((G ^ (ix & 7)) << 4)) = v;
      }
    }
  };

  auto stage_w = [&](int st, int buf) {
    int hh = st / 9, tap = st - hh * 9;
    if (WT) {
      const short* base = wt + (size_t)tap * (COUT*CIN)
                             + (size_t)(cblk*128) * CIN + hh * 64;
      #pragma unroll
      for (int it = 0; it < 4; ++it) {
        int slot = it * 256 + tid;            // 1024 slots of 16B
        int c = slot >> 3, gsw = (slot & 7) ^ (c & 7);
        gload16(base + c * CIN + gsw * 8, sw + buf*WB + slot * 16);
      }
    } else {
      #pragma unroll
      for (int it = 0; it < 4; ++it) {
        int slot = it * 256 + tid;
        int c = slot >> 3, gsw = (slot & 7) ^ (c & 7);
        int cout = cblk*128 + c;
        short8 v;
        #pragma unroll
        for (int j = 0; j < 8; ++j) {
          int cin = hh*64 + gsw*8 + j;
          v[j] = f2b(wgt[cout*(CIN*KHW) + cin*KHW + tap]);
        }
        *(short8*)(sw + buf*WB + slot * 16) = v;
      }
    }
  };

  const int lane = tid & 63;
  const int wid  = tid >> 6;      // 0..3
  const int wm = wid >> 1;        // 0..1 -> couts [wm*64, +64) of block's 128
  const int wn = wid & 1;         // 0..1 -> rows [wn*4, +4)
  const int l15 = lane & 15;
  const int kgrp = lane >> 4;     // 0..3
  const int l7 = l15 & 7;

  int arow[4];
  #pragma unroll
  for (int mi = 0; mi < 4; ++mi) arow[mi] = (wm*64 + mi*16 + l15) * 128;

  f32x4 acc[4][NREP] = {};

  stage_x(0);
  stage_w(0, 0);
  __syncthreads();

  for (int st = 0; st < 18; ++st) {          // 2 cin-halves x 9 taps
    const int tap = st % 9;
    const int kh = tap / 3, kw = tap - (tap/3)*3;
    const char* swb = sw + (st & 1) * WB;
    const int brow = (4*wn + kh) * ROWB_;

    #pragma unroll
    for (int s = 0; s < 2; ++s) {            // two K=32 steps over 64 cins
      const int g = s*4 + kgrp;
      const int akey = (g ^ l7) << 4;
      const int bkey = (g ^ ((l15 + kw) & 7)) << 4;
      const char* ab = swb + akey;
      const char* bb0 = sx + brow + (l15 + kw)*128 + bkey;

      short8 a[4];
      #pragma unroll
      for (int mi = 0; mi < 4; ++mi)
        a[mi] = *(const short8*)(ab + arow[mi]);
      short8 bf[NREP];
      #pragma unroll
      for (int r = 0; r < 4; ++r) {          // all offsets = imm
        if (NCG == 2) {
          bf[2*r]   = *(const short8*)(bb0 + r*ROWB_);
          bf[2*r+1] = *(const short8*)(bb0 + 16*128 + r*ROWB_);
        } else {
          bf[r]     = *(const short8*)(bb0 + r*ROWB_);
        }
      }

      if (s == 0 && st + 1 < 18)             // issue w-DMA off critical path
        stage_w(st + 1, (st + 1) & 1);

      __builtin_amdgcn_s_setprio(1);
      #pragma unroll
      for (int mi = 0; mi < 4; ++mi)
        #pragma unroll
        for (int ni = 0; ni < NREP; ++ni)
          acc[mi][ni] = __builtin_amdgcn_mfma_f32_16x16x32_bf16(
              a[mi], bf[ni], acc[mi][ni], 0, 0, 0);
      __builtin_amdgcn_s_setprio(0);
    }

    if (st == 8) {
      __syncthreads();      // x half-0 readers done; w(9) DMA drained here
      stage_x(1);
      __syncthreads();      // drains x half-1 DMA
    } else {
      __syncthreads();
    }
  }

  // ---- epilogue: C layout col=l15 (px), row=4*kgrp+r (cout) [m89] ----
  float* ob = out + (size_t)b * COUT * (OH*OW);
  #pragma unroll
  for (int ni = 0; ni < NREP; ++ni) {
    int oh = h0 + 4*wn + (NCG == 2 ? (ni >> 1) : ni);
    int ow = w0 + (NCG == 2 ? (ni & 1)*16 : 0) + l15;
    if (oh < OH && ow < OW) {
      #pragma unroll
      for (int mi = 0; mi < 4; ++mi) {
        #pragma unroll
        for (int r = 0; r < 4; ++r) {
          int cout = cblk*128 + wm*64 + mi*16 + kgrp*4 + r;
          ob[(size_t)cout*(OH*OW) + oh*OW + ow] = acc[mi][ni][r];
        }
      }
    }
  }
}

template<bool XT, bool WT>
__global__ __launch_bounds__(256, 2)
void conv_main(const float* __restrict__ x, const float* __restrict__ wgt,
               const short* __restrict__ wt, const short* __restrict__ xt,
               const short* __restrict__ zp, float* __restrict__ out) {
  __shared__ __align__(16) char smem[XBMAX + 2*WB];   // 76288 B, 2 blocks/CU

  const int tid = threadIdx.x;

  // XCD-chunked bijective swizzle (3584 % 8 == 0)
  const int nb  = gridDim.x;
  const int swz = (blockIdx.x & 7) * (nb >> 3) + (blockIdx.x >> 3);
  const int b    = swz / 112;            // 2 cblk * 4 tw * 14 th
  const int rem  = swz - b * 112;
  const int cblk = rem / 56;
  const int rem2 = rem - cblk * 56;
  const int t_w  = rem2 / 14;
  const int t_h  = rem2 - t_w * 14;
  const int h0 = t_h * TH;

  if (t_w == 3) {
    conv_tile<1, XT, WT>(smem, x, wgt, wt, xt, zp, out, b, cblk, h0, 96, tid);
  } else {
    conv_tile<2, XT, WT>(smem, x, wgt, wt, xt, zp, out, b, cblk, h0,
                         t_w * 32, tid);
  }
}

// one-time weight transpose+cvt: wt[tap][cout][cin] bf16; also zeros the
// 256-B zero page that follows wt in the workspace.
__global__ void wprep(const float* __restrict__ wgt, short* __restrict__ wt,
                      short* __restrict__ zp) {
  int idx = blockIdx.x * 256 + threadIdx.x;
  if (idx < 128) zp[idx] = 0;
  if (idx >= KHW*COUT*CIN) return;
  int khw  = idx / (COUT*CIN);
  int rem  = idx - khw*(COUT*CIN);
  int cout = rem >> 7, cin = rem & 127;
  wt[idx] = f2b(wgt[cout*(CIN*KHW) + cin*KHW + khw]);
}

// one-time x transpose+cvt: xt[b][h][w][cin] bf16, via padded LDS tile.
__global__ __launch_bounds__(256)
void xprep(const float* __restrict__ x, short* __restrict__ xt) {
  __shared__ short lsh[CIN * 113];   // 28928 B
  const int bh = blockIdx.x;
  const int b = bh / H, h = bh - b * H;
  const float* src = x + ((size_t)b * CIN * H + h) * W;
  for (int u = threadIdx.x; u < CIN * W; u += 256) {
    int c = u / W, w = u - c * W;
    lsh[c * 113 + w] = f2b(src[(size_t)c * (H*W) + w]);
  }
  __syncthreads();
  short* dst = xt + (size_t)bh * (W * CIN);
  for (int o = threadIdx.x; o < W * CIN / 8; o += 256) {   // 1792
    int w = o >> 4, s = o & 15;
    short8 v;
    #pragma unroll
    for (int j = 0; j < 8; ++j) v[j] = lsh[(s*8 + j) * 113 + w];
    *(short8*)(dst + o * 8) = v;
  }
}

extern "C" void kernel_launch(void* const* d_in, const int* in_sizes, int n_in,
                              void* d_out, int out_size, void* d_ws, size_t ws_size,
                              hipStream_t stream) {
  const float* x   = (const float*)d_in[0];
  const float* wgt = (const float*)d_in[1];
  float* out = (float*)d_out;
  const size_t wt_bytes = (size_t)(KHW*COUT*CIN) * sizeof(short);   // 589824
  const size_t zp_bytes = 256;
  const size_t xt_bytes = (size_t)32 * H * W * CIN * sizeof(short); // 102.76 MB
  dim3 grid(3584);   // 2 cblk x 4 tw x 14 th x 32 b
  if (ws_size >= wt_bytes + zp_bytes + xt_bytes) {
    short* wt = (short*)d_ws;
    short* zp = (short*)((char*)d_ws + wt_bytes);
    short* xt = (short*)((char*)d_ws + wt_bytes + zp_bytes);
    wprep<<<(KHW*COUT*CIN + 255)/256, 256, 0, stream>>>(wgt, wt, zp);
    xprep<<<32 * H, 256, 0, stream>>>(x, xt);
    conv_main<true, true><<<grid, 256, 0, stream>>>(x, wgt, wt, xt, zp, out);
  } else if (ws_size >= wt_bytes + zp_bytes) {
    short* wt = (short*)d_ws;
    short* zp = (short*)((char*)d_ws + wt_bytes);
    wprep<<<(KHW*COUT*CIN + 255)/256, 256, 0, stream>>>(wgt, wt, zp);
    conv_main<false, true><<<grid, 256, 0, stream>>>(x, wgt, wt, nullptr, zp, out);
  } else {
    conv_main<false, false><<<grid, 256, 0, stream>>>(x, wgt, nullptr, nullptr, nullptr, out);
  }
}